// Round 8
// baseline (5942.714 us; speedup 1.0000x reference)
//
#include <hip/hip_runtime.h>
#include <math.h>

// Problem constants (fixed by the reference)
#define T_STEPS 512
#define BATCH   64
#define HID     512
#define NROW    2048          // 4*HID rows of concatenated W
#define HHIST   16777216ULL   // T*B*H floats (offset of i_hist in d_out)

// fast-path geometry
#define GROUPS  4             // batch groups of 16
#define GB      16            // batch per group
#define UW      16            // units per wg
#define WPG     32            // wgs per group (32*16 = 512 units)

typedef __attribute__((ext_vector_type(8))) short short8_t;   // 8 bf16
typedef __attribute__((ext_vector_type(4))) float float4_t;   // MFMA acc

// ---------------------------------------------------------------------------
// helpers
// ---------------------------------------------------------------------------
__device__ __forceinline__ float sigf(float z) {
  z = fminf(fmaxf(z, -30.f), 30.f);
  return 1.f / (1.f + __expf(-z));
}
__device__ __forceinline__ float tanhf_(float v) {
  v = fminf(fmaxf(v, -15.f), 15.f);
  const float e = __expf(2.f * v);
  return (e - 1.f) / (e + 1.f);
}
__device__ __forceinline__ unsigned short bf16hi(float f) {
  unsigned u = __float_as_uint(f);
  return (unsigned short)((u + 0x7fffu + ((u >> 16) & 1u)) >> 16);  // RNE
}
__device__ __forceinline__ float bf16f(unsigned short h) {
  return __uint_as_float(((unsigned)h) << 16);
}
// pack f as (hi bf16 << 16) | (lo bf16): hi + lo ~ f to ~2^-17 rel.
__device__ __forceinline__ unsigned packh(float f) {
  unsigned short h = bf16hi(f);
  unsigned short l = bf16hi(f - bf16f(h));
  return (((unsigned)h) << 16) | (unsigned)l;
}

// ---------------------------------------------------------------------------
// Kernel A: Zx[t][g][r][b16] = b[r] + sum_k Wx[r][k]*x[t][g*16+b16][k]
// Layout now [t][4 groups][2048 rows][16 b] to match the MFMA rec kernel.
// ---------------------------------------------------------------------------
__global__ __launch_bounds__(256) void xgemm_kernel(
    const float* __restrict__ x,
    const float* __restrict__ Wf, const float* __restrict__ Wi,
    const float* __restrict__ Wo, const float* __restrict__ Wc,
    const float* __restrict__ bf, const float* __restrict__ bi,
    const float* __restrict__ bo, const float* __restrict__ bc,
    float* __restrict__ Zx)
{
  const int rtile = blockIdx.x;   // 0..15
  const int t     = blockIdx.y;   // 0..511
  const int g  = rtile >> 2;
  const int n0 = (rtile & 3) * 128;
  const float* Wg = (g == 0) ? Wf : (g == 1) ? Wi : (g == 2) ? Wo : Wc;
  const float* bg = (g == 0) ? bf : (g == 1) ? bi : (g == 2) ? bo : bc;

  __shared__ float Wt[32][132];   // [k][r] transposed, padded
  __shared__ float Xt[32][68];    // [k][b] transposed, padded

  const int tid = threadIdx.x;
  const int tr  = tid & 31;       // 4 r-rows each
  const int tb  = tid >> 5;       // 8 b-cols each

  float acc[4][8];
#pragma unroll
  for (int i = 0; i < 4; ++i)
#pragma unroll
    for (int j = 0; j < 8; ++j) acc[i][j] = 0.f;

  float biasv[4];
#pragma unroll
  for (int i = 0; i < 4; ++i) biasv[i] = bg[n0 + tr * 4 + i];

  const float* xt = x + (size_t)t * (BATCH * 512);

  for (int kc = 0; kc < 512; kc += 32) {
#pragma unroll
    for (int p = 0; p < 4; ++p) {
      const int r  = p * 32 + (tid >> 3);
      const int kk = (tid & 7) * 4;
      float4 v = *(const float4*)&Wg[(size_t)(n0 + r) * 1024 + 512 + kc + kk];
      Wt[kk + 0][r] = v.x; Wt[kk + 1][r] = v.y;
      Wt[kk + 2][r] = v.z; Wt[kk + 3][r] = v.w;
    }
    {
      const int b  = tid >> 2;
      const int kk = (tid & 3) * 8;
      float4 v0 = *(const float4*)&xt[b * 512 + kc + kk];
      float4 v1 = *(const float4*)&xt[b * 512 + kc + kk + 4];
      Xt[kk + 0][b] = v0.x; Xt[kk + 1][b] = v0.y;
      Xt[kk + 2][b] = v0.z; Xt[kk + 3][b] = v0.w;
      Xt[kk + 4][b] = v1.x; Xt[kk + 5][b] = v1.y;
      Xt[kk + 6][b] = v1.z; Xt[kk + 7][b] = v1.w;
    }
    __syncthreads();
#pragma unroll
    for (int kk = 0; kk < 32; ++kk) {
      float4 wv = *(const float4*)&Wt[kk][tr * 4];
      float4 x0 = *(const float4*)&Xt[kk][tb * 8];
      float4 x1 = *(const float4*)&Xt[kk][tb * 8 + 4];
      const float wa[4] = {wv.x, wv.y, wv.z, wv.w};
      const float xa[8] = {x0.x, x0.y, x0.z, x0.w, x1.x, x1.y, x1.z, x1.w};
#pragma unroll
      for (int i = 0; i < 4; ++i)
#pragma unroll
        for (int j = 0; j < 8; ++j)
          acc[i][j] = fmaf(wa[i], xa[j], acc[i][j]);
    }
    __syncthreads();
  }

  const int rg = g * 512 + n0 + tr * 4;
#pragma unroll
  for (int ir = 0; ir < 4; ++ir) {
    const float bv = biasv[ir];
    float4 o0 = make_float4(acc[ir][0] + bv, acc[ir][1] + bv,
                            acc[ir][2] + bv, acc[ir][3] + bv);
    float4 o1 = make_float4(acc[ir][4] + bv, acc[ir][5] + bv,
                            acc[ir][6] + bv, acc[ir][7] + bv);
    // [t][group = tb>>1][row][16 b]; b-in-group = (tb&1)*8 + j
    float* dst = Zx + ((((size_t)t * 4 + (tb >> 1)) * NROW + rg + ir) * 16 +
                       (tb & 1) * 8);
    *(float4*)dst       = o0;
    *(float4*)(dst + 4) = o1;
  }
}

// ---------------------------------------------------------------------------
// Kernel B (fast): MFMA recurrence. 4 groups x 32 wgs; wg = 512 thr (8 waves),
// owns units [n0, n0+16) x 4 gates = 64 rows. Wave wv: gate = wv>>1,
// k-half = wv&1; its A-fragments (16 rows x 256 k, bf16 hi+lo) live in
// 64 VGPRs for the whole kernel (weight-stationary).
// h exchange: epoch-tagged u64 = (epoch<<32)|(bf16hi<<16 | bf16lo), sc1
// write-through to MALL (round-7 protocol, same safety invariant). Staged
// to XOR-swizzled LDS bf16 planes [b][k]; B-fragments via ds_read_b128.
// Split GEMM: z_h = Whi*hhi + Whi*hlo + Wlo*hhi  (~fp32 accuracy).
// Cross-k-half reduce + gates on 256 threads; 2 barriers/step.
// ---------------------------------------------------------------------------
__global__ __launch_bounds__(512, 2) void lstm_rec_fast(
    const float* __restrict__ mask,
    const float* __restrict__ Wf, const float* __restrict__ Wi,
    const float* __restrict__ Wo, const float* __restrict__ Wc,
    const float* __restrict__ Zx,
    unsigned long long* __restrict__ hP,   // [2][4][16 b][512 k] tagged pairs
    float* __restrict__ out)
{
  __shared__ __align__(16) short hip_[16 * 512];  // hi plane [b][k] swizzled
  __shared__ __align__(16) short lop_[16 * 512];  // lo plane
  __shared__ float zp[4][2][16][17];              // [gate][khalf][u][b pad]

  const int tid  = threadIdx.x;
  const int w    = blockIdx.x;        // 0..127
  const int g    = w & 3;             // batch group
  const int iw   = w >> 2;            // 0..31
  const int n0   = iw * UW;           // first unit of this wg

  const int wv   = tid >> 6;          // wave 0..7
  const int lane = tid & 63;
  const int gmt  = wv >> 1;           // gate of this wave (0=f,1=i,2=o,3=c)
  const int kh   = wv & 1;            // k-half (0: k<256, 1: k>=256)
  const int kb   = lane >> 4;         // k-block 0..3
  const int l15  = lane & 15;

  // ---- A fragments: Ahi/Alo[w8], lane holds A[m=l15][k=k0+kb*8+j]
  const float* Wm4 = (gmt == 0) ? Wf : (gmt == 1) ? Wi : (gmt == 2) ? Wo : Wc;
  const float* Wrow = Wm4 + (size_t)(n0 + l15) * 1024;   // h-part = cols 0..511
  short8_t Ahi[8], Alo[8];
#pragma unroll
  for (int w8 = 0; w8 < 8; ++w8) {
    const int base = kh * 256 + w8 * 32 + kb * 8;
#pragma unroll
    for (int j = 0; j < 8; ++j) {
      const float f = Wrow[base + j];
      const unsigned short h = bf16hi(f);
      Ahi[w8][j] = (short)h;
      Alo[w8][j] = (short)bf16hi(f - bf16f(h));
    }
  }

  // epilogue identity (threads 0..255): b_e = tid>>4, u_e = tid&15
  const int b_e = tid >> 4, u_e = tid & 15;
  float c_r = 0.f, h_r = 0.f;

  // staging identity: b_s row, 16-k run
  const int b_s = tid >> 5;            // 0..15
  const int kr  = (tid & 31) * 16;     // k start
  char* hib = (char*)hip_;
  char* lob = (char*)lop_;
  const int rowS = b_s * 1024;         // 512 bf16 = 1024 B per b-row
  const int xrS  = (b_s & 7) << 4;
  const int oS   = kr * 2;

  // dot-side B addressing: row = l15 (batch col), same swizzle
  const int rowB = l15 * 1024;
  const int xrB  = (l15 & 7) << 4;

  for (int t = 0; t < T_STEPS; ++t) {
    // ---- early loads (consumed in epilogue; overlap the poll)
    float zxv[4]; float mval = 0.f;
    if (tid < 256) {
      mval = mask[t * 64 + g * GB + b_e];
#pragma unroll
      for (int g4 = 0; g4 < 4; ++g4)
        zxv[g4] = Zx[(((size_t)t * 4 + g) * NROW + g4 * 512 + n0 + u_e) * 16 + b_e];
    }

    // ---- stage h^t: poll 16 tagged pairs, unpack to bf16 planes
    {
      unsigned long long* hq =
          hP + ((((size_t)(t & 1) * 4 + g) * 16 + b_s) * 512 + kr);
      unsigned p[16];
      while (true) {
        unsigned long long q[16];
#pragma unroll
        for (int j = 0; j < 16; ++j)
          q[j] = __hip_atomic_load(hq + j, __ATOMIC_RELAXED,
                                   __HIP_MEMORY_SCOPE_AGENT);
        bool ok = true;
#pragma unroll
        for (int j = 0; j < 16; ++j)
          ok &= ((unsigned)(q[j] >> 32) == (unsigned)t);
        if (ok) {
#pragma unroll
          for (int j = 0; j < 16; ++j) p[j] = (unsigned)q[j];
          break;
        }
        __builtin_amdgcn_s_sleep(1);
      }
      short8_t H0, H1, L0, L1;
#pragma unroll
      for (int j = 0; j < 8; ++j) {
        H0[j] = (short)(p[j] >> 16);     L0[j] = (short)(p[j] & 0xffffu);
        H1[j] = (short)(p[j + 8] >> 16); L1[j] = (short)(p[j + 8] & 0xffffu);
      }
      // lane-parity chunk order: each ds_write hits all 8 bank groups
      const int pa = (lane & 1) << 4;
      *(short8_t*)(hib + rowS + ((oS + pa) ^ xrS))        = (lane & 1) ? H1 : H0;
      *(short8_t*)(hib + rowS + ((oS + (pa ^ 16)) ^ xrS)) = (lane & 1) ? H0 : H1;
      *(short8_t*)(lob + rowS + ((oS + pa) ^ xrS))        = (lane & 1) ? L1 : L0;
      *(short8_t*)(lob + rowS + ((oS + (pa ^ 16)) ^ xrS)) = (lane & 1) ? L0 : L1;
    }
    __syncthreads();   // planes ready (also: zp reads of step t-1 all done)

    // ---- MFMA dot: this wave's 16x16 D over its 256-k half, 3-pass split
    {
      float4_t c0 = {0.f, 0.f, 0.f, 0.f}, c1 = {0.f, 0.f, 0.f, 0.f};
#pragma unroll
      for (int w8 = 0; w8 < 8; ++w8) {
        const int o = kh * 512 + w8 * 64 + kb * 16;   // byte offset in b-row
        const short8_t bh = *(const short8_t*)(hib + rowB + (o ^ xrB));
        const short8_t bl = *(const short8_t*)(lob + rowB + (o ^ xrB));
        if (w8 & 1) {
          c1 = __builtin_amdgcn_mfma_f32_16x16x32_bf16(Ahi[w8], bh, c1, 0, 0, 0);
          c1 = __builtin_amdgcn_mfma_f32_16x16x32_bf16(Ahi[w8], bl, c1, 0, 0, 0);
          c1 = __builtin_amdgcn_mfma_f32_16x16x32_bf16(Alo[w8], bh, c1, 0, 0, 0);
        } else {
          c0 = __builtin_amdgcn_mfma_f32_16x16x32_bf16(Ahi[w8], bh, c0, 0, 0, 0);
          c0 = __builtin_amdgcn_mfma_f32_16x16x32_bf16(Ahi[w8], bl, c0, 0, 0, 0);
          c0 = __builtin_amdgcn_mfma_f32_16x16x32_bf16(Alo[w8], bh, c0, 0, 0, 0);
        }
      }
      // D layout: lane holds D[m=(l>>4)*4+r][n=l15]; m = unit, n = batch
#pragma unroll
      for (int r = 0; r < 4; ++r)
        zp[gmt][kh][kb * 4 + r][l15] = c0[r] + c1[r];
    }
    __syncthreads();   // zp complete

    // ---- epilogue: 256 threads, one (unit,batch) each
    if (tid < 256) {
      float z[4];
#pragma unroll
      for (int g4 = 0; g4 < 4; ++g4)
        z[g4] = zxv[g4] + zp[g4][0][u_e][b_e] + zp[g4][1][u_e][b_e];
      const float f  = sigf(z[0]);
      const float ig = sigf(z[1]);
      const float o  = sigf(z[2]);
      const float ct = tanhf_(z[3]);
      float cn = f * c_r + ig * ct;
      cn = mval * cn + (1.f - mval) * c_r;
      c_r = cn;
      float hn = o * tanhf_(cn);
      hn = mval * hn + (1.f - mval) * h_r;
      h_r = hn;
      // publish h^{t+1}: tagged, fire-and-forget (round-7 protocol)
      const size_t hidx =
          (((size_t)((t + 1) & 1) * 4 + g) * 16 + b_e) * 512 + (n0 + u_e);
      const unsigned long long pk =
          (((unsigned long long)(unsigned)(t + 1)) << 32) |
          (unsigned long long)packh(hn);
      __hip_atomic_store(hP + hidx, pk, __ATOMIC_RELAXED,
                         __HIP_MEMORY_SCOPE_AGENT);
      // history outputs (nontemporal, off the chain)
      const size_t ob = ((size_t)t * 64 + g * GB + b_e) * 512 + (n0 + u_e);
      __builtin_nontemporal_store(hn, &out[ob]);
      __builtin_nontemporal_store(ig, &out[HHIST + ob]);
    }
    // next iteration's stage may overwrite planes immediately: all plane
    // reads (dot) finished before the zp barrier above. zp is overwritten
    // only after the next post-stage barrier.
  }
}

// ---------------------------------------------------------------------------
// Fallback (ws too small): round-3 inline-x cooperative version, verbatim.
// ---------------------------------------------------------------------------
__device__ __forceinline__ void grid_barrier(unsigned* cnt, int w, int tid, int round) {
  __syncthreads();
  if (tid == 0) {
    __builtin_amdgcn_fence(__ATOMIC_RELEASE, "agent");
    unsigned* gc = cnt + 16 + ((w >> 4) << 5);
    unsigned prev = __hip_atomic_fetch_add(gc, 1u, __ATOMIC_RELAXED,
                                           __HIP_MEMORY_SCOPE_AGENT);
    if ((prev & 15u) == 15u)
      __hip_atomic_fetch_add(cnt, 1u, __ATOMIC_RELAXED,
                             __HIP_MEMORY_SCOPE_AGENT);
    const unsigned target = (unsigned)(round + 1) * 16u;
    while (__hip_atomic_load(cnt, __ATOMIC_RELAXED,
                             __HIP_MEMORY_SCOPE_AGENT) < target)
      __builtin_amdgcn_s_sleep(2);
    __builtin_amdgcn_fence(__ATOMIC_ACQUIRE, "agent");
  }
  __syncthreads();
}

__global__ __launch_bounds__(512) void lstm_rec_inline(
    const float* __restrict__ x,  const float* __restrict__ mask,
    const float* __restrict__ Wf, const float* __restrict__ Wi,
    const float* __restrict__ Wo, const float* __restrict__ Wc,
    const float* __restrict__ bf, const float* __restrict__ bi,
    const float* __restrict__ bo, const float* __restrict__ bc,
    float* __restrict__ hT, unsigned* __restrict__ cnt,
    float* __restrict__ out)
{
  constexpr int WC = 1024;
  __shared__ float Wlds[8 * WC];
  __shared__ float zpart[8 * 8 * 64];

  const int tid = threadIdx.x;
  const int w   = blockIdx.x;
  const int kq  = tid >> 6;
  const int b   = tid & 63;
  const int n0  = ((w & 7) << 6) + ((w >> 3) << 1);

#pragma unroll
  for (int i = 0; i < WC / 256; ++i) {
    const int idx4 = tid + (i << 9);
    const int rr   = idx4 / (WC / 4);
    const int col  = (idx4 % (WC / 4)) * 4;
    const int g = rr >> 1, u = rr & 1;
    const float* Wrow =
        ((g == 0) ? Wf : (g == 1) ? Wi : (g == 2) ? Wo : Wc) +
        (size_t)(n0 + u) * 1024;
    *(float4*)&Wlds[rr * WC + col] = *(const float4*)&Wrow[col];
  }

  float biasv[4] = {0.f, 0.f, 0.f, 0.f};
  float c_r = 0.f, h_r = 0.f;
  if (tid < 128) {
    const int u = tid >> 6;
    biasv[0] = bf[n0 + u]; biasv[1] = bi[n0 + u];
    biasv[2] = bo[n0 + u]; biasv[3] = bc[n0 + u];
  }
  __syncthreads();

  for (int t = 0; t < T_STEPS; ++t) {
    float zpre[4] = {0.f, 0.f, 0.f, 0.f};
    float mval = 0.f;
    if (tid < 128) {
      const int bb = tid & 63;
      mval = mask[t * 64 + bb];
#pragma unroll
      for (int g = 0; g < 4; ++g) zpre[g] = biasv[g];
    }

    float acc[8];
#pragma unroll
    for (int rr = 0; rr < 8; ++rr) acc[rr] = 0.f;

    {
      const float* hcur = hT + ((t & 1) << 15);
      const int k0 = kq << 6;
#pragma unroll
      for (int k4 = 0; k4 < 16; ++k4) {
        const int k = k0 + (k4 << 2);
        const float h0 = hcur[(k + 0) * 64 + b];
        const float h1 = hcur[(k + 1) * 64 + b];
        const float h2 = hcur[(k + 2) * 64 + b];
        const float h3 = hcur[(k + 3) * 64 + b];
#pragma unroll
        for (int rr = 0; rr < 8; ++rr) {
          float4 wv = *(const float4*)&Wlds[rr * WC + k];
          acc[rr] = fmaf(h0, wv.x, acc[rr]);
          acc[rr] = fmaf(h1, wv.y, acc[rr]);
          acc[rr] = fmaf(h2, wv.z, acc[rr]);
          acc[rr] = fmaf(h3, wv.w, acc[rr]);
        }
      }
    }
    {
      const float* xt = x + (size_t)t * (64 * 512) + b * 512;
      const int k0 = kq << 6;
#pragma unroll
      for (int k4 = 0; k4 < 16; ++k4) {
        const int k = k0 + (k4 << 2);
        float4 xv = *(const float4*)&xt[k];
#pragma unroll
        for (int rr = 0; rr < 8; ++rr) {
          float4 wv = *(const float4*)&Wlds[rr * WC + 512 + k];
          acc[rr] = fmaf(xv.x, wv.x, acc[rr]);
          acc[rr] = fmaf(xv.y, wv.y, acc[rr]);
          acc[rr] = fmaf(xv.z, wv.z, acc[rr]);
          acc[rr] = fmaf(xv.w, wv.w, acc[rr]);
        }
      }
    }

#pragma unroll
    for (int rr = 0; rr < 8; ++rr)
      zpart[((kq << 3) + rr) * 64 + b] = acc[rr];
    __syncthreads();

    if (tid < 128) {
      const int u = tid >> 6, bb = tid & 63;
      float z[4];
#pragma unroll
      for (int g = 0; g < 4; ++g) {
        const int rr = g * 2 + u;
        float s = zpre[g];
#pragma unroll
        for (int q = 0; q < 8; ++q) s += zpart[((q << 3) + rr) * 64 + bb];
        z[g] = s;
      }
      const float f  = sigf(z[0]);
      const float ig = sigf(z[1]);
      const float o  = sigf(z[2]);
      const float ct = tanhf_(z[3]);
      float cn = f * c_r + ig * ct;
      cn = mval * cn + (1.f - mval) * c_r;
      c_r = cn;
      float hn = o * tanhf_(cn);
      hn = mval * hn + (1.f - mval) * h_r;
      h_r = hn;
      const int n = n0 + u;
      hT[(((t + 1) & 1) << 15) + n * 64 + bb] = hn;
      out[((size_t)t * 64 + bb) * 512 + n]         = hn;
      out[HHIST + ((size_t)t * 64 + bb) * 512 + n] = ig;
    }

    if (t != T_STEPS - 1) grid_barrier(cnt, w, tid, t);
  }
}

// ---------------------------------------------------------------------------
// launch
// ---------------------------------------------------------------------------
extern "C" void kernel_launch(void* const* d_in, const int* in_sizes, int n_in,
                              void* d_out, int out_size, void* d_ws, size_t ws_size,
                              hipStream_t stream) {
  (void)in_sizes; (void)n_in; (void)out_size;
  // setup_inputs order: x, mask, Wf, bf, Wi, bi, Wc, bc, Wo, bo
  const float* x    = (const float*)d_in[0];
  const float* mask = (const float*)d_in[1];
  const float* Wf   = (const float*)d_in[2];
  const float* bf   = (const float*)d_in[3];
  const float* Wi   = (const float*)d_in[4];
  const float* bi   = (const float*)d_in[5];
  const float* Wc   = (const float*)d_in[6];
  const float* bc   = (const float*)d_in[7];
  const float* Wo   = (const float*)d_in[8];
  const float* bo   = (const float*)d_in[9];
  float* out = (float*)d_out;

  const size_t zx_bytes = (size_t)T_STEPS * NROW * 64 * 4;      // 256 MiB
  const size_t hp_bytes = (size_t)2 * GROUPS * GB * 512 * 8;    // 512 KiB
  const bool fast = ws_size >= zx_bytes + hp_bytes;

  if (fast) {
    float* Zx = (float*)d_ws;
    unsigned long long* hP = (unsigned long long*)((char*)d_ws + zx_bytes);
    // zero tagged buffer: epoch 0, h = 0 is the t=0 initial state
    hipMemsetAsync(hP, 0, hp_bytes, stream);
    hipLaunchKernelGGL(xgemm_kernel, dim3(16, 512), dim3(256), 0, stream,
                       x, Wf, Wi, Wo, Wc, bf, bi, bo, bc, Zx);
    void* kargs[] = { (void*)&mask, (void*)&Wf, (void*)&Wi, (void*)&Wo,
                      (void*)&Wc, (void*)&Zx, (void*)&hP, (void*)&out };
    hipLaunchCooperativeKernel(reinterpret_cast<void*>(&lstm_rec_fast),
                               dim3(128), dim3(512), kargs, 0, stream);
  } else {
    float* hT = (float*)d_ws;
    const size_t h_bytes = 2 * 64 * 512 * 4;                    // 256 KiB
    unsigned* cnt = (unsigned*)((char*)hT + h_bytes);
    hipMemsetAsync(hT, 0, h_bytes + 4096, stream);
    void* kargs[] = { (void*)&x, (void*)&mask, (void*)&Wf, (void*)&Wi,
                      (void*)&Wo, (void*)&Wc, (void*)&bf, (void*)&bi,
                      (void*)&bo, (void*)&bc, (void*)&hT, (void*)&cnt,
                      (void*)&out };
    hipLaunchCooperativeKernel(reinterpret_cast<void*>(&lstm_rec_inline),
                               dim3(256), dim3(512), kargs, 0, stream);
  }
}

// Round 9
// 4639.895 us; speedup vs baseline: 1.2808x; 1.2808x over previous
//
#include <hip/hip_runtime.h>
#include <math.h>

// Problem constants (fixed by the reference)
#define T_STEPS 512
#define BATCH   64
#define HID     512
#define NROW    2048          // 4*HID rows of concatenated W
#define HHIST   16777216ULL   // T*B*H floats (offset of i_hist in d_out)

typedef __attribute__((ext_vector_type(8))) short short8_t;   // 8 bf16
typedef __attribute__((ext_vector_type(4))) float float4_t;   // MFMA acc

// ---------------------------------------------------------------------------
// helpers
// ---------------------------------------------------------------------------
__device__ __forceinline__ float sigf(float z) {
  z = fminf(fmaxf(z, -30.f), 30.f);
  return 1.f / (1.f + __expf(-z));
}
__device__ __forceinline__ float tanhf_(float v) {
  v = fminf(fmaxf(v, -15.f), 15.f);
  const float e = __expf(2.f * v);
  return (e - 1.f) / (e + 1.f);
}
__device__ __forceinline__ unsigned short bf16hi(float f) {
  unsigned u = __float_as_uint(f);
  return (unsigned short)((u + 0x7fffu + ((u >> 16) & 1u)) >> 16);  // RNE
}
__device__ __forceinline__ float bf16f(unsigned short h) {
  return __uint_as_float(((unsigned)h) << 16);
}
// pack f as (hi bf16 << 16) | (lo bf16): hi + lo ~ f to ~2^-17 rel.
__device__ __forceinline__ unsigned packh(float f) {
  unsigned short h = bf16hi(f);
  unsigned short l = bf16hi(f - bf16f(h));
  return (((unsigned)h) << 16) | (unsigned)l;
}

// ---------------------------------------------------------------------------
// Kernel A (round-7 version): Zx[t][g][r][b8] = b[r] + sum_k Wx[r][k]*x[..]
// Layout [t][8 groups][2048 rows][8 b] — dense per-group lines.
// ---------------------------------------------------------------------------
__global__ __launch_bounds__(256) void xgemm_kernel(
    const float* __restrict__ x,
    const float* __restrict__ Wf, const float* __restrict__ Wi,
    const float* __restrict__ Wo, const float* __restrict__ Wc,
    const float* __restrict__ bf, const float* __restrict__ bi,
    const float* __restrict__ bo, const float* __restrict__ bc,
    float* __restrict__ Zx)
{
  const int rtile = blockIdx.x;   // 0..15
  const int t     = blockIdx.y;   // 0..511
  const int g  = rtile >> 2;
  const int n0 = (rtile & 3) * 128;
  const float* Wg = (g == 0) ? Wf : (g == 1) ? Wi : (g == 2) ? Wo : Wc;
  const float* bg = (g == 0) ? bf : (g == 1) ? bi : (g == 2) ? bo : bc;

  __shared__ float Wt[32][132];   // [k][r] transposed, padded
  __shared__ float Xt[32][68];    // [k][b] transposed, padded

  const int tid = threadIdx.x;
  const int tr  = tid & 31;       // 4 r-rows each
  const int tb  = tid >> 5;       // 8 b-cols each (= batch group tb)

  float acc[4][8];
#pragma unroll
  for (int i = 0; i < 4; ++i)
#pragma unroll
    for (int j = 0; j < 8; ++j) acc[i][j] = 0.f;

  float biasv[4];
#pragma unroll
  for (int i = 0; i < 4; ++i) biasv[i] = bg[n0 + tr * 4 + i];

  const float* xt = x + (size_t)t * (BATCH * 512);

  for (int kc = 0; kc < 512; kc += 32) {
#pragma unroll
    for (int p = 0; p < 4; ++p) {
      const int r  = p * 32 + (tid >> 3);
      const int kk = (tid & 7) * 4;
      float4 v = *(const float4*)&Wg[(size_t)(n0 + r) * 1024 + 512 + kc + kk];
      Wt[kk + 0][r] = v.x; Wt[kk + 1][r] = v.y;
      Wt[kk + 2][r] = v.z; Wt[kk + 3][r] = v.w;
    }
    {
      const int b  = tid >> 2;
      const int kk = (tid & 3) * 8;
      float4 v0 = *(const float4*)&xt[b * 512 + kc + kk];
      float4 v1 = *(const float4*)&xt[b * 512 + kc + kk + 4];
      Xt[kk + 0][b] = v0.x; Xt[kk + 1][b] = v0.y;
      Xt[kk + 2][b] = v0.z; Xt[kk + 3][b] = v0.w;
      Xt[kk + 4][b] = v1.x; Xt[kk + 5][b] = v1.y;
      Xt[kk + 6][b] = v1.z; Xt[kk + 7][b] = v1.w;
    }
    __syncthreads();
#pragma unroll
    for (int kk = 0; kk < 32; ++kk) {
      float4 wv = *(const float4*)&Wt[kk][tr * 4];
      float4 x0 = *(const float4*)&Xt[kk][tb * 8];
      float4 x1 = *(const float4*)&Xt[kk][tb * 8 + 4];
      const float wa[4] = {wv.x, wv.y, wv.z, wv.w};
      const float xa[8] = {x0.x, x0.y, x0.z, x0.w, x1.x, x1.y, x1.z, x1.w};
#pragma unroll
      for (int i = 0; i < 4; ++i)
#pragma unroll
        for (int j = 0; j < 8; ++j)
          acc[i][j] = fmaf(wa[i], xa[j], acc[i][j]);
    }
    __syncthreads();
  }

  const int rg = g * 512 + n0 + tr * 4;
#pragma unroll
  for (int ir = 0; ir < 4; ++ir) {
    const float bv = biasv[ir];
    float4 o0 = make_float4(acc[ir][0] + bv, acc[ir][1] + bv,
                            acc[ir][2] + bv, acc[ir][3] + bv);
    float4 o1 = make_float4(acc[ir][4] + bv, acc[ir][5] + bv,
                            acc[ir][6] + bv, acc[ir][7] + bv);
    // [t][group = tb][row][8 b]
    float* dst = Zx + (((size_t)t * 8 + tb) * NROW + rg + ir) * 8;
    *(float4*)dst       = o0;
    *(float4*)(dst + 4) = o1;
  }
}

// ---------------------------------------------------------------------------
// Kernel B (fast): MFMA recurrence with round-7 topology.
// 8 XCD-pure groups (g = w&7) x 32 wgs; wg owns units [n0,n0+16) x 4 gates
// x 8 batch. 8 waves: gate = wv>>1, k-half = wv&1. A-fragments (16 units x
// 256 k, bf16 hi+lo) resident in 64 VGPRs (weight-stationary).
// h exchange: epoch-tagged u64 (epoch<<32 | bf16hi<<16 | bf16lo), relaxed
// sc1 agent atomics (round-7 protocol; full-slab polling preserves the
// double-buffer invariant: publishing t+1 implies every wg staged t,
// implies every wg finished reading t-1 from buf[(t+1)&1]).
// Split GEMM: z_h = Whi*hhi + Whi*hlo + Wlo*hhi (~fp32 accuracy).
// ---------------------------------------------------------------------------
__global__ __launch_bounds__(512) void lstm_rec_fast(
    const float* __restrict__ mask,
    const float* __restrict__ Wf, const float* __restrict__ Wi,
    const float* __restrict__ Wo, const float* __restrict__ Wc,
    const float* __restrict__ Zx,
    unsigned long long* __restrict__ hP,   // [2][8 g][8 b][512 k] tagged
    float* __restrict__ out)
{
  __shared__ __align__(16) short hip_[8 * 512];   // hi plane [b][k] swizzled
  __shared__ __align__(16) short lop_[8 * 512];   // lo plane
  __shared__ float zp[4][2][16][9];               // [gate][kh][u][b pad]

  const int tid  = threadIdx.x;
  const int w    = blockIdx.x;        // 0..255
  const int g    = w & 7;             // batch group (XCD-pure)
  const int iw   = w >> 3;            // 0..31
  const int n0   = iw * 16;           // first unit of this wg

  const int wv   = tid >> 6;          // wave 0..7
  const int lane = tid & 63;
  const int gmt  = wv >> 1;           // gate (0=f,1=i,2=o,3=c)
  const int kh   = wv & 1;            // k-half
  const int kb   = lane >> 4;         // k-block 0..3
  const int l15  = lane & 15;

  // ---- A fragments: lane holds A[m=l15][k=kh*256+s*32+kb*8+j]
  const float* Wm4 = (gmt == 0) ? Wf : (gmt == 1) ? Wi : (gmt == 2) ? Wo : Wc;
  const float* Wrow = Wm4 + (size_t)(n0 + l15) * 1024;   // h-part cols 0..511
  short8_t Ahi[8], Alo[8];
#pragma unroll
  for (int s = 0; s < 8; ++s) {
    const int base = kh * 256 + s * 32 + kb * 8;
#pragma unroll
    for (int j = 0; j < 8; ++j) {
      const float f = Wrow[base + j];
      const unsigned short h = bf16hi(f);
      Ahi[s][j] = (short)h;
      Alo[s][j] = (short)bf16hi(f - bf16f(h));
    }
  }

  // staging identity: thread owns (b_s, kr..kr+7)
  const int b_s = tid >> 6;            // 0..7
  const int kr  = (tid & 63) * 8;      // k start
  char* hib = (char*)hip_;
  char* lob = (char*)lop_;
  const int sOff = b_s * 1024 + ((kr * 2) ^ ((b_s & 7) << 4));

  // epilogue identity (tid < 128): u_e = tid&15, b_e = tid>>4
  const int u_e = tid & 15, b_e = tid >> 4;
  float c_r = 0.f, h_r = 0.f;

  for (int t = 0; t < T_STEPS; ++t) {
    // ---- early loads (consumed in epilogue; overlap the poll)
    float zxv[4] = {0.f, 0.f, 0.f, 0.f};
    float mval = 0.f;
    if (tid < 128) {
      mval = mask[t * 64 + g * 8 + b_e];
#pragma unroll
      for (int g4 = 0; g4 < 4; ++g4)
        zxv[g4] = Zx[(((size_t)t * 8 + g) * NROW + g4 * 512 + n0 + u_e) * 8 + b_e];
    }

    // ---- stage h^t: poll 8 tagged pairs (one 64B row), unpack to planes
    {
      unsigned long long* hq =
          hP + (((size_t)(t & 1) * 8 + g) * 8 + b_s) * 512 + kr;
      unsigned long long q[8];
      while (true) {
#pragma unroll
        for (int j = 0; j < 8; ++j)
          q[j] = __hip_atomic_load(hq + j, __ATOMIC_RELAXED,
                                   __HIP_MEMORY_SCOPE_AGENT);
        bool ok = true;
#pragma unroll
        for (int j = 0; j < 8; ++j)
          ok &= ((unsigned)(q[j] >> 32) == (unsigned)t);
        if (ok) break;
        __builtin_amdgcn_s_sleep(1);
      }
      short8_t H, L;
#pragma unroll
      for (int j = 0; j < 8; ++j) {
        const unsigned p = (unsigned)q[j];
        H[j] = (short)(p >> 16);
        L[j] = (short)(p & 0xffffu);
      }
      *(short8_t*)(hib + sOff) = H;
      *(short8_t*)(lob + sOff) = L;
    }
    __syncthreads();   // S1: planes ready (and zp reads of t-1 all done)

    // ---- MFMA dot: 16 units x 8 batch over this wave's 256-k half
    {
      float4_t c0 = {0.f, 0.f, 0.f, 0.f}, c1 = {0.f, 0.f, 0.f, 0.f};
      const int bcol = l15 & 7;                    // lanes 8-15 duplicate
      const int bbase = bcol * 1024;
      const int xr = bcol << 4;
#pragma unroll
      for (int s = 0; s < 8; ++s) {
        const int o = kh * 512 + s * 64 + kb * 16;
        const short8_t bh = *(const short8_t*)(hib + bbase + (o ^ xr));
        const short8_t bl = *(const short8_t*)(lob + bbase + (o ^ xr));
        if (s & 1) {
          c1 = __builtin_amdgcn_mfma_f32_16x16x32_bf16(Ahi[s], bh, c1, 0, 0, 0);
          c1 = __builtin_amdgcn_mfma_f32_16x16x32_bf16(Ahi[s], bl, c1, 0, 0, 0);
          c1 = __builtin_amdgcn_mfma_f32_16x16x32_bf16(Alo[s], bh, c1, 0, 0, 0);
        } else {
          c0 = __builtin_amdgcn_mfma_f32_16x16x32_bf16(Ahi[s], bh, c0, 0, 0, 0);
          c0 = __builtin_amdgcn_mfma_f32_16x16x32_bf16(Ahi[s], bl, c0, 0, 0, 0);
          c0 = __builtin_amdgcn_mfma_f32_16x16x32_bf16(Alo[s], bh, c0, 0, 0, 0);
        }
      }
      // D: lane holds D[m=kb*4+r][n=l15]; m = unit, n = batch (8 valid)
      if (l15 < 8) {
#pragma unroll
        for (int r = 0; r < 4; ++r)
          zp[gmt][kh][kb * 4 + r][l15] = c0[r] + c1[r];
      }
    }
    __syncthreads();   // S2: zp complete

    // ---- epilogue: 128 threads, one (unit, batch) each
    if (tid < 128) {
      float z[4];
#pragma unroll
      for (int g4 = 0; g4 < 4; ++g4)
        z[g4] = zxv[g4] + zp[g4][0][u_e][b_e] + zp[g4][1][u_e][b_e];
      const float f  = sigf(z[0]);
      const float ig = sigf(z[1]);
      const float o  = sigf(z[2]);
      const float ct = tanhf_(z[3]);
      float cn = f * c_r + ig * ct;
      cn = mval * cn + (1.f - mval) * c_r;
      c_r = cn;
      float hn = o * tanhf_(cn);
      hn = mval * hn + (1.f - mval) * h_r;
      h_r = hn;
      // publish h^{t+1}: tagged, fire-and-forget
      const size_t hidx =
          (((size_t)((t + 1) & 1) * 8 + g) * 8 + b_e) * 512 + (n0 + u_e);
      const unsigned long long pk =
          (((unsigned long long)(unsigned)(t + 1)) << 32) |
          (unsigned long long)packh(hn);
      __hip_atomic_store(hP + hidx, pk, __ATOMIC_RELAXED,
                         __HIP_MEMORY_SCOPE_AGENT);
      // history outputs (nontemporal, off the chain)
      const size_t ob = ((size_t)t * 64 + g * 8 + b_e) * 512 + (n0 + u_e);
      __builtin_nontemporal_store(hn, &out[ob]);
      __builtin_nontemporal_store(ig, &out[HHIST + ob]);
    }
  }
}

// ---------------------------------------------------------------------------
// Fallback (ws too small): round-3 inline-x cooperative version, verbatim.
// ---------------------------------------------------------------------------
__device__ __forceinline__ void grid_barrier(unsigned* cnt, int w, int tid, int round) {
  __syncthreads();
  if (tid == 0) {
    __builtin_amdgcn_fence(__ATOMIC_RELEASE, "agent");
    unsigned* gc = cnt + 16 + ((w >> 4) << 5);
    unsigned prev = __hip_atomic_fetch_add(gc, 1u, __ATOMIC_RELAXED,
                                           __HIP_MEMORY_SCOPE_AGENT);
    if ((prev & 15u) == 15u)
      __hip_atomic_fetch_add(cnt, 1u, __ATOMIC_RELAXED,
                             __HIP_MEMORY_SCOPE_AGENT);
    const unsigned target = (unsigned)(round + 1) * 16u;
    while (__hip_atomic_load(cnt, __ATOMIC_RELAXED,
                             __HIP_MEMORY_SCOPE_AGENT) < target)
      __builtin_amdgcn_s_sleep(2);
    __builtin_amdgcn_fence(__ATOMIC_ACQUIRE, "agent");
  }
  __syncthreads();
}

__global__ __launch_bounds__(512) void lstm_rec_inline(
    const float* __restrict__ x,  const float* __restrict__ mask,
    const float* __restrict__ Wf, const float* __restrict__ Wi,
    const float* __restrict__ Wo, const float* __restrict__ Wc,
    const float* __restrict__ bf, const float* __restrict__ bi,
    const float* __restrict__ bo, const float* __restrict__ bc,
    float* __restrict__ hT, unsigned* __restrict__ cnt,
    float* __restrict__ out)
{
  constexpr int WC = 1024;
  __shared__ float Wlds[8 * WC];
  __shared__ float zpart[8 * 8 * 64];

  const int tid = threadIdx.x;
  const int w   = blockIdx.x;
  const int kq  = tid >> 6;
  const int b   = tid & 63;
  const int n0  = ((w & 7) << 6) + ((w >> 3) << 1);

#pragma unroll
  for (int i = 0; i < WC / 256; ++i) {
    const int idx4 = tid + (i << 9);
    const int rr   = idx4 / (WC / 4);
    const int col  = (idx4 % (WC / 4)) * 4;
    const int g = rr >> 1, u = rr & 1;
    const float* Wrow =
        ((g == 0) ? Wf : (g == 1) ? Wi : (g == 2) ? Wo : Wc) +
        (size_t)(n0 + u) * 1024;
    *(float4*)&Wlds[rr * WC + col] = *(const float4*)&Wrow[col];
  }

  float biasv[4] = {0.f, 0.f, 0.f, 0.f};
  float c_r = 0.f, h_r = 0.f;
  if (tid < 128) {
    const int u = tid >> 6;
    biasv[0] = bf[n0 + u]; biasv[1] = bi[n0 + u];
    biasv[2] = bo[n0 + u]; biasv[3] = bc[n0 + u];
  }
  __syncthreads();

  for (int t = 0; t < T_STEPS; ++t) {
    float zpre[4] = {0.f, 0.f, 0.f, 0.f};
    float mval = 0.f;
    if (tid < 128) {
      const int bb = tid & 63;
      mval = mask[t * 64 + bb];
#pragma unroll
      for (int g = 0; g < 4; ++g) zpre[g] = biasv[g];
    }

    float acc[8];
#pragma unroll
    for (int rr = 0; rr < 8; ++rr) acc[rr] = 0.f;

    {
      const float* hcur = hT + ((t & 1) << 15);
      const int k0 = kq << 6;
#pragma unroll
      for (int k4 = 0; k4 < 16; ++k4) {
        const int k = k0 + (k4 << 2);
        const float h0 = hcur[(k + 0) * 64 + b];
        const float h1 = hcur[(k + 1) * 64 + b];
        const float h2 = hcur[(k + 2) * 64 + b];
        const float h3 = hcur[(k + 3) * 64 + b];
#pragma unroll
        for (int rr = 0; rr < 8; ++rr) {
          float4 wv = *(const float4*)&Wlds[rr * WC + k];
          acc[rr] = fmaf(h0, wv.x, acc[rr]);
          acc[rr] = fmaf(h1, wv.y, acc[rr]);
          acc[rr] = fmaf(h2, wv.z, acc[rr]);
          acc[rr] = fmaf(h3, wv.w, acc[rr]);
        }
      }
    }
    {
      const float* xt = x + (size_t)t * (64 * 512) + b * 512;
      const int k0 = kq << 6;
#pragma unroll
      for (int k4 = 0; k4 < 16; ++k4) {
        const int k = k0 + (k4 << 2);
        float4 xv = *(const float4*)&xt[k];
#pragma unroll
        for (int rr = 0; rr < 8; ++rr) {
          float4 wv = *(const float4*)&Wlds[rr * WC + 512 + k];
          acc[rr] = fmaf(xv.x, wv.x, acc[rr]);
          acc[rr] = fmaf(xv.y, wv.y, acc[rr]);
          acc[rr] = fmaf(xv.z, wv.z, acc[rr]);
          acc[rr] = fmaf(xv.w, wv.w, acc[rr]);
        }
      }
    }

#pragma unroll
    for (int rr = 0; rr < 8; ++rr)
      zpart[((kq << 3) + rr) * 64 + b] = acc[rr];
    __syncthreads();

    if (tid < 128) {
      const int u = tid >> 6, bb = tid & 63;
      float z[4];
#pragma unroll
      for (int g = 0; g < 4; ++g) {
        const int rr = g * 2 + u;
        float s = zpre[g];
#pragma unroll
        for (int q = 0; q < 8; ++q) s += zpart[((q << 3) + rr) * 64 + bb];
        z[g] = s;
      }
      const float f  = sigf(z[0]);
      const float ig = sigf(z[1]);
      const float o  = sigf(z[2]);
      const float ct = tanhf_(z[3]);
      float cn = f * c_r + ig * ct;
      cn = mval * cn + (1.f - mval) * c_r;
      c_r = cn;
      float hn = o * tanhf_(cn);
      hn = mval * hn + (1.f - mval) * h_r;
      h_r = hn;
      const int n = n0 + u;
      hT[(((t + 1) & 1) << 15) + n * 64 + bb] = hn;
      out[((size_t)t * 64 + bb) * 512 + n]         = hn;
      out[HHIST + ((size_t)t * 64 + bb) * 512 + n] = ig;
    }

    if (t != T_STEPS - 1) grid_barrier(cnt, w, tid, t);
  }
}

// ---------------------------------------------------------------------------
// launch
// ---------------------------------------------------------------------------
extern "C" void kernel_launch(void* const* d_in, const int* in_sizes, int n_in,
                              void* d_out, int out_size, void* d_ws, size_t ws_size,
                              hipStream_t stream) {
  (void)in_sizes; (void)n_in; (void)out_size;
  // setup_inputs order: x, mask, Wf, bf, Wi, bi, Wc, bc, Wo, bo
  const float* x    = (const float*)d_in[0];
  const float* mask = (const float*)d_in[1];
  const float* Wf   = (const float*)d_in[2];
  const float* bf   = (const float*)d_in[3];
  const float* Wi   = (const float*)d_in[4];
  const float* bi   = (const float*)d_in[5];
  const float* Wc   = (const float*)d_in[6];
  const float* bc   = (const float*)d_in[7];
  const float* Wo   = (const float*)d_in[8];
  const float* bo   = (const float*)d_in[9];
  float* out = (float*)d_out;

  const size_t zx_bytes = (size_t)T_STEPS * NROW * 64 * 4;      // 256 MiB
  const size_t hp_bytes = (size_t)2 * 8 * 8 * 512 * 8;          // 512 KiB
  const bool fast = ws_size >= zx_bytes + hp_bytes;

  if (fast) {
    float* Zx = (float*)d_ws;
    unsigned long long* hP = (unsigned long long*)((char*)d_ws + zx_bytes);
    // zero tagged buffer: epoch 0, h = 0 is the t=0 initial state
    hipMemsetAsync(hP, 0, hp_bytes, stream);
    hipLaunchKernelGGL(xgemm_kernel, dim3(16, 512), dim3(256), 0, stream,
                       x, Wf, Wi, Wo, Wc, bf, bi, bo, bc, Zx);
    void* kargs[] = { (void*)&mask, (void*)&Wf, (void*)&Wi, (void*)&Wo,
                      (void*)&Wc, (void*)&Zx, (void*)&hP, (void*)&out };
    hipLaunchCooperativeKernel(reinterpret_cast<void*>(&lstm_rec_fast),
                               dim3(256), dim3(512), kargs, 0, stream);
  } else {
    float* hT = (float*)d_ws;
    const size_t h_bytes = 2 * 64 * 512 * 4;                    // 256 KiB
    unsigned* cnt = (unsigned*)((char*)hT + h_bytes);
    hipMemsetAsync(hT, 0, h_bytes + 4096, stream);
    void* kargs[] = { (void*)&x, (void*)&mask, (void*)&Wf, (void*)&Wi,
                      (void*)&Wo, (void*)&Wc, (void*)&bf, (void*)&bi,
                      (void*)&bo, (void*)&bc, (void*)&hT, (void*)&cnt,
                      (void*)&out };
    hipLaunchCooperativeKernel(reinterpret_cast<void*>(&lstm_rec_inline),
                               dim3(256), dim3(512), kargs, 0, stream);
  }
}